// Round 10
// baseline (640.060 us; speedup 1.0000x reference)
//
#include <hip/hip_runtime.h>

typedef unsigned short u16;
typedef unsigned int u32;

#define HID 128

static inline int cdiv(long long a, int b) { return (int)((a + b - 1) / b); }

__device__ __forceinline__ float bfbits(u32 u) { union { u32 u; float f; } c; c.u = u; return c.f; }
__device__ __forceinline__ u16 f2bf(float f) {
  union { float f; u32 u; } c; c.f = f;
  u32 u = c.u;
  return (u16)((u + 0x7fffu + ((u >> 16) & 1u)) >> 16);  // RNE
}
__device__ __forceinline__ u32 pack2bf(float a, float b) {
  return (u32)f2bf(a) | ((u32)f2bf(b) << 16);
}

// ---------- GEMM + attention epilogue (unchanged from round 9) ----------
template <int COUT, int HEADS>
__global__ __launch_bounds__(256) void gemm_attn(
    const float* __restrict__ Hin, const float* __restrict__ W,
    const float* __restrict__ attS, const float* __restrict__ attD,
    u16* __restrict__ XL, float* __restrict__ aS, float* __restrict__ aD, int n) {
  constexpr int TN = COUT / 8;
  constexpr int TM = 256 / TN;
  constexpr int MT = TM * 8;
  constexpr int HALF = COUT / 2;
  constexpr int C = COUT / HEADS;
  constexpr bool SAMEHEAD = (HALF < C);

  __shared__ float xs[32][MT + 4];
  __shared__ float ws[32][COUT];

  int t = threadIdx.x;
  int tx = t % TN, ty = t / TN;
  int rowBase = blockIdx.x * MT;

  float acc[8][8];
#pragma unroll
  for (int r = 0; r < 8; ++r)
#pragma unroll
    for (int c = 0; c < 8; ++c) acc[r][c] = 0.f;

  for (int kb = 0; kb < 4; ++kb) {
    __syncthreads();
    {
      int kg = (t & 7) * 4;
#pragma unroll
      for (int pass = 0; pass < MT / 32; ++pass) {
        int rr = pass * 32 + (t >> 3);
        int grow = rowBase + rr;
        float4 v = make_float4(0.f, 0.f, 0.f, 0.f);
        if (grow < n) v = *(const float4*)(Hin + (size_t)grow * HID + kb * 32 + kg);
        xs[kg + 0][rr] = v.x;
        xs[kg + 1][rr] = v.y;
        xs[kg + 2][rr] = v.z;
        xs[kg + 3][rr] = v.w;
      }
    }
    {
      constexpr int WF = 32 * COUT / 256;
      const float* wp = W + (size_t)kb * 32 * COUT;
      float* wsf = &ws[0][0];
#pragma unroll
      for (int u = 0; u < WF; u += 4) {
        int idx = t * WF + u;
        *(float4*)(wsf + idx) = *(const float4*)(wp + idx);
      }
    }
    __syncthreads();
#pragma unroll 8
    for (int k = 0; k < 32; ++k) {
      const float4 xv0 = *(const float4*)&xs[k][ty * 8];
      const float4 xv1 = *(const float4*)&xs[k][ty * 8 + 4];
      const float4 wv0 = *(const float4*)&ws[k][tx * 4];
      const float4 wv1 = *(const float4*)&ws[k][HALF + tx * 4];
      const float xr[8] = {xv0.x, xv0.y, xv0.z, xv0.w, xv1.x, xv1.y, xv1.z, xv1.w};
      const float wc[8] = {wv0.x, wv0.y, wv0.z, wv0.w, wv1.x, wv1.y, wv1.z, wv1.w};
#pragma unroll
      for (int r = 0; r < 8; ++r)
#pragma unroll
        for (int c = 0; c < 8; ++c) acc[r][c] += xr[r] * wc[c];
    }
  }

  float sv[8], dv[8];
#pragma unroll
  for (int j = 0; j < 4; ++j) {
    sv[j] = attS[tx * 4 + j];
    sv[4 + j] = attS[HALF + tx * 4 + j];
    dv[j] = attD[tx * 4 + j];
    dv[4 + j] = attD[HALF + tx * 4 + j];
  }
  int row0 = rowBase + ty * 8;
  int hlo = (tx * 4) / C;
  int hhi = (HALF + tx * 4) / C;
  u32* XLo = (u32*)XL;
#pragma unroll
  for (int r = 0; r < 8; ++r) {
    int row = row0 + r;
    bool ok = (row < n);
    if (ok) {
      u32 lo01 = pack2bf(acc[r][0], acc[r][1]);
      u32 lo23 = pack2bf(acc[r][2], acc[r][3]);
      u32 hi01 = pack2bf(acc[r][4], acc[r][5]);
      u32 hi23 = pack2bf(acc[r][6], acc[r][7]);
      *(uint2*)(XLo + (size_t)row * (COUT / 2) + tx * 2) = make_uint2(lo01, lo23);
      *(uint2*)(XLo + (size_t)row * (COUT / 2) + COUT / 4 + tx * 2) = make_uint2(hi01, hi23);
    }
    float pslo = acc[r][0] * sv[0] + acc[r][1] * sv[1] + acc[r][2] * sv[2] + acc[r][3] * sv[3];
    float pshi = acc[r][4] * sv[4] + acc[r][5] * sv[5] + acc[r][6] * sv[6] + acc[r][7] * sv[7];
    float pdlo = acc[r][0] * dv[0] + acc[r][1] * dv[1] + acc[r][2] * dv[2] + acc[r][3] * dv[3];
    float pdhi = acc[r][4] * dv[4] + acc[r][5] * dv[5] + acc[r][6] * dv[6] + acc[r][7] * dv[7];
    if (SAMEHEAD) { pslo += pshi; pdlo += pdhi; }
#pragma unroll
    for (int mk = 1; mk < 8; mk <<= 1) {
      pslo += __shfl_xor(pslo, mk);
      pdlo += __shfl_xor(pdlo, mk);
      if (!SAMEHEAD) {
        pshi += __shfl_xor(pshi, mk);
        pdhi += __shfl_xor(pdhi, mk);
      }
    }
    if (((tx & 7) == 0) && ok) {
      aS[(size_t)row * HEADS + hlo] = pslo;
      aD[(size_t)row * HEADS + hlo] = pdlo;
      if (!SAMEHEAD) {
        aS[(size_t)row * HEADS + hhi] = pshi;
        aD[(size_t)row * HEADS + hhi] = pdhi;
      }
    }
  }
}

// ---------- merged CSR build for all 3 layers (blockIdx.y = layer) ----------
__global__ void hist_all(const int* __restrict__ ei, int* __restrict__ degAll,
                         int e4, int rem, int E, int N) {
  int L = blockIdx.y;
  const int* dst = ei + (size_t)(2 * L + 1) * E;
  int* deg = degAll + L * N;
  int i = blockIdx.x * blockDim.x + threadIdx.x;
  if (i < e4) {
    int4 d = ((const int4*)dst)[i];
    atomicAdd(&deg[d.x], 1);
    atomicAdd(&deg[d.y], 1);
    atomicAdd(&deg[d.z], 1);
    atomicAdd(&deg[d.w], 1);
  } else if (i - e4 < rem) {
    atomicAdd(&deg[dst[e4 * 4 + (i - e4)]], 1);
  }
}

// scan over all 3N degrees; +1 per node reserves the self-loop slot.
__global__ __launch_bounds__(256) void scan_block(const int* __restrict__ deg, int* __restrict__ out,
                                                  int* __restrict__ bsum, int n) {
  int t = threadIdx.x;
  int base = blockIdx.x * 1024 + t * 4;
  int v[4];
#pragma unroll
  for (int u = 0; u < 4; ++u) v[u] = (base + u < n) ? (deg[base + u] + 1) : 0;
  int s = v[0] + v[1] + v[2] + v[3];
  int lane = t & 63;
  int inc = s;
#pragma unroll
  for (int off = 1; off < 64; off <<= 1) {
    int w = __shfl_up(inc, (unsigned)off, 64);
    if (lane >= off) inc += w;
  }
  __shared__ int wsum[4];
  int wid = t >> 6;
  if (lane == 63) wsum[wid] = inc;
  __syncthreads();
  if (t == 0) {
    int a = 0;
#pragma unroll
    for (int i = 0; i < 4; ++i) { int tmp = wsum[i]; wsum[i] = a; a += tmp; }
  }
  __syncthreads();
  int wOff = wsum[wid];
  int run = wOff + inc - s;
#pragma unroll
  for (int u = 0; u < 4; ++u) {
    if (base + u < n) out[base + u] = run;
    run += v[u];
  }
  if (t == 255) bsum[blockIdx.x] = wOff + inc;
}

__global__ void scan_sums(int* __restrict__ bsum, int nb) {
  if (threadIdx.x == 0 && blockIdx.x == 0) {
    int a = 0;
    for (int i = 0; i < nb; ++i) { int t = bsum[i]; bsum[i] = a; a += t; }
  }
}

// finalize indptr; write self-loop at segment head (coalesced-ish, no atomic);
// cursor starts one past the self-loop slot. blockIdx.y = layer.
__global__ void scan_add_loops(int* __restrict__ indptr, const int* __restrict__ bsum,
                               int* __restrict__ cursor, int* __restrict__ srcIdx,
                               int N, int total) {
  int L = blockIdx.y;
  int t = blockIdx.x * blockDim.x + threadIdx.x;
  if (t < N) {
    int i = L * N + t;
    int v = indptr[i] + bsum[i >> 10];
    indptr[i] = v;
    cursor[i] = v + 1;
    srcIdx[v] = t;  // self loop first in segment
  }
  if (L == 0 && t == 0) indptr[3 * N] = total;
}

// merged scatter: edges only (self loops already placed). blockIdx.y = layer.
__global__ void scatter_all(const int* __restrict__ ei, int* __restrict__ cursorAll,
                            int* __restrict__ srcIdx, int e4, int rem, int E, int N) {
  int L = blockIdx.y;
  const int* src = ei + (size_t)(2 * L) * E;
  const int* dst = src + E;
  int* cursor = cursorAll + L * N;
  int i = blockIdx.x * blockDim.x + threadIdx.x;
  if (i < e4) {
    int4 d = ((const int4*)dst)[i];
    int4 s = ((const int4*)src)[i];
    int p0 = atomicAdd(&cursor[d.x], 1);
    int p1 = atomicAdd(&cursor[d.y], 1);
    int p2 = atomicAdd(&cursor[d.z], 1);
    int p3 = atomicAdd(&cursor[d.w], 1);
    srcIdx[p0] = s.x;
    srcIdx[p1] = s.y;
    srcIdx[p2] = s.z;
    srcIdx[p3] = s.w;
  } else if (i - e4 < rem) {
    int ei2 = e4 * 4 + (i - e4);
    int p = atomicAdd(&cursor[dst[ei2]], 1);
    srcIdx[p] = src[ei2];
  }
}

// ---------- aggregation (unchanged from round 9) ----------
template <int COUT, int HEADS, bool RELU>
__global__ __launch_bounds__(256) void aggregate(
    const u16* __restrict__ XL, const float* __restrict__ aS, const float* __restrict__ aD,
    const int* __restrict__ indptr, const int* __restrict__ srcIdx,
    const float* __restrict__ bias, float* __restrict__ outF, int n) {
  constexpr int VPL = COUT / 64;
  constexpr int C = COUT / HEADS;
  int wave = (blockIdx.x * blockDim.x + threadIdx.x) >> 6;
  if (wave >= n) return;
  int lane = threadIdx.x & 63;
  int i = wave;
  int col = lane * VPL;
  int h = col / C;
  float ad = aD[i * HEADS + h];
  float s = 0.f, acc0 = 0.f, acc1 = 0.f;
  int e0 = indptr[i], e1 = indptr[i + 1];
  int idx = e0;
  const u32* XL32 = (const u32*)XL;

  for (; idx + 8 <= e1; idx += 8) {
    int j[8];
#pragma unroll
    for (int u = 0; u < 8; ++u) j[u] = srcIdx[idx + u];
    float a[8];
#pragma unroll
    for (int u = 0; u < 8; ++u) a[u] = aS[j[u] * HEADS + h];
    if (VPL == 2) {
      u32 px[8];
#pragma unroll
      for (int u = 0; u < 8; ++u) px[u] = XL32[j[u] * (COUT / 2) + lane];
#pragma unroll
      for (int u = 0; u < 8; ++u) {
        float l = a[u] + ad;
        l = (l >= 0.f) ? l : 0.2f * l;
        float el = __expf(fminf(l, 60.f));
        s += el;
        acc0 += el * bfbits(px[u] << 16);
        acc1 += el * bfbits(px[u] & 0xffff0000u);
      }
    } else {
      u16 px[8];
#pragma unroll
      for (int u = 0; u < 8; ++u) px[u] = XL[j[u] * COUT + lane];
#pragma unroll
      for (int u = 0; u < 8; ++u) {
        float l = a[u] + ad;
        l = (l >= 0.f) ? l : 0.2f * l;
        float el = __expf(fminf(l, 60.f));
        s += el;
        acc0 += el * bfbits(((u32)px[u]) << 16);
      }
    }
  }
  for (; idx < e1; ++idx) {
    int j = srcIdx[idx];
    float l = aS[j * HEADS + h] + ad;
    l = (l >= 0.f) ? l : 0.2f * l;
    float el = __expf(fminf(l, 60.f));
    s += el;
    if (VPL == 2) {
      u32 px = XL32[j * (COUT / 2) + lane];
      acc0 += el * bfbits(px << 16);
      acc1 += el * bfbits(px & 0xffff0000u);
    } else {
      acc0 += el * bfbits(((u32)XL[j * COUT + lane]) << 16);
    }
  }

  float inv = 1.f / (s + 1e-16f);
  float o0 = acc0 * inv + bias[col];
  if (RELU) o0 = fmaxf(o0, 0.f);
  if (VPL == 2) {
    float o1 = acc1 * inv + bias[col + 1];
    if (RELU) o1 = fmaxf(o1, 0.f);
    *(float2*)(outF + ((size_t)i * COUT + col)) = make_float2(o0, o1);
  } else {
    outF[(size_t)i * COUT + col] = o0;
  }
}

extern "C" void kernel_launch(void* const* d_in, const int* in_sizes, int n_in,
                              void* d_out, int out_size, void* d_ws, size_t ws_size,
                              hipStream_t stream) {
  const float* x = (const float*)d_in[0];
  const int* ei = (const int*)d_in[1];
  const float* W1 = (const float*)d_in[2];
  const float* as1 = (const float*)d_in[3];
  const float* ad1 = (const float*)d_in[4];
  const float* b1 = (const float*)d_in[5];
  const float* W2 = (const float*)d_in[6];
  const float* as2 = (const float*)d_in[7];
  const float* ad2 = (const float*)d_in[8];
  const float* b2 = (const float*)d_in[9];
  const float* W3 = (const float*)d_in[10];
  const float* as3 = (const float*)d_in[11];
  const float* ad3 = (const float*)d_in[12];
  const float* b3 = (const float*)d_in[13];

  int N = in_sizes[0] / HID;  // x is [N,128]
  int E = in_sizes[1] / 6;    // edge_indices is [3,2,E]

  char* w = (char*)d_ws;
  auto alloc = [&](size_t bytes) {
    void* q = (void*)w;
    w += (bytes + 255) & ~(size_t)255;
    return q;
  };
  float* bufH = (float*)alloc((size_t)N * HID * 4);
  u16* bufXL = (u16*)alloc((size_t)N * HID * 2);
  float* aS = (float*)alloc((size_t)N * 4 * 4);
  float* aD = (float*)alloc((size_t)N * 4 * 4);
  int* degAll = (int*)alloc((size_t)3 * N * 4);      // doubles as raw indptr after scan_block
  int* indptrAll = (int*)alloc(((size_t)3 * N + 1) * 4);
  int* cursorAll = (int*)alloc((size_t)3 * N * 4);
  int* bsum = (int*)alloc(512 * 4);
  int* srcIdxAll = (int*)alloc((size_t)3 * (E + N) * 4);

  int e4 = ((E & 3) == 0) ? (E >> 2) : 0;
  int rem = E - e4 * 4;
  int n3 = 3 * N;
  int total = 3 * (E + N);

  // ---- merged CSR build for all 3 layers ----
  hipMemsetAsync(degAll, 0, (size_t)n3 * 4, stream);
  {
    dim3 g(cdiv((long long)e4 + rem, 256), 3);
    hist_all<<<g, 256, 0, stream>>>(ei, degAll, e4, rem, E, N);
  }
  int nb = cdiv(n3, 1024);
  scan_block<<<nb, 256, 0, stream>>>(degAll, indptrAll, bsum, n3);
  scan_sums<<<1, 64, 0, stream>>>(bsum, nb);
  {
    dim3 g(cdiv(N, 256), 3);
    scan_add_loops<<<g, 256, 0, stream>>>(indptrAll, bsum, cursorAll, srcIdxAll, N, total);
  }
  {
    dim3 g(cdiv((long long)e4 + rem, 256), 3);
    scatter_all<<<g, 256, 0, stream>>>(ei, cursorAll, srcIdxAll, e4, rem, E, N);
  }

  // ---- layer 1 ----
  gemm_attn<128, 4><<<cdiv(N, 128), 256, 0, stream>>>(x, W1, as1, ad1, bufXL, aS, aD, N);
  aggregate<128, 4, true><<<cdiv(N, 4), 256, 0, stream>>>(bufXL, aS, aD, indptrAll + 0 * N,
                                                          srcIdxAll, b1, bufH, N);
  // ---- layer 2 ----
  gemm_attn<128, 4><<<cdiv(N, 128), 256, 0, stream>>>(bufH, W2, as2, ad2, bufXL, aS, aD, N);
  aggregate<128, 4, true><<<cdiv(N, 4), 256, 0, stream>>>(bufXL, aS, aD, indptrAll + 1 * N,
                                                          srcIdxAll, b2, bufH, N);
  // ---- layer 3 ----
  gemm_attn<64, 1><<<cdiv(N, 256), 256, 0, stream>>>(bufH, W3, as3, ad3, bufXL, aS, aD, N);
  aggregate<64, 1, false><<<cdiv(N, 4), 256, 0, stream>>>(bufXL, aS, aD, indptrAll + 2 * N,
                                                          srcIdxAll, b3, (float*)d_out, N);
}